// Round 12
// baseline (279.422 us; speedup 1.0000x reference)
//
#include <hip/hip_runtime.h>
#include <hip/hip_bf16.h>
#include <cstdint>
#include <cstddef>

// ---------------------------------------------------------------------------
// LSTM cell: ht = sigmoid(o) * tanh(sigmoid(f)*c + sigmoid(i)*sigmoid(c~))
// gates = [prev_state, x] @ W'^T, W' gate-interleaved AND stored in
// MFMA-fragment-linear order: 16B unit (n16, ks, lane) at
// ((n16*128 + ks)*64 + lane)*16, lane = (k_chunk<<4) | row_in_16.
// B operands load straight from global into registers (coalesced 1024 B per
// wave-load, 2-region lead) — B never touches LDS. A stays LDS-staged (gll).
// LDS traffic per K-tile drops 256->160 KB; MFMA becomes the floor.
// vmcnt ledger (issue/iter: r1 B4, r2 G2, r3 B4+G2, r5 B4, r6 G2, r7 B4+G2):
// every A-half has ops-after = 12 at its certifying barrier -> uniform
// VMW12 before the BAR at each even region end; prologue VMW8.
// B RAW waits are compiler-tracked register deps.
// ---------------------------------------------------------------------------

typedef __bf16 nbf16;
typedef nbf16 bf16x8 __attribute__((ext_vector_type(8)));
typedef float f32x4 __attribute__((ext_vector_type(4)));

static constexpr int MDIM = 4096;
static constexpr int NDIM = 8192;
static constexpr int KDIM = 4096;
static constexpr int HDIM = 2048;
static constexpr int KB   = KDIM * 2;     // K row stride in bytes

#define VMW12 asm volatile("s_waitcnt vmcnt(12)" ::: "memory")
#define VMW8  asm volatile("s_waitcnt vmcnt(8)" ::: "memory")
#define VMW0  asm volatile("s_waitcnt vmcnt(0)" ::: "memory")
#define LGKM0 asm volatile("s_waitcnt lgkmcnt(0)" ::: "memory")
#define BAR   __builtin_amdgcn_s_barrier()
#define SB0   __builtin_amdgcn_sched_barrier(0)
#define PRIO1 __builtin_amdgcn_s_setprio(1)
#define PRIO0 __builtin_amdgcn_s_setprio(0)

__device__ __forceinline__ void async16(void* lds, const void* g) {
    __builtin_amdgcn_global_load_lds(
        (const __attribute__((address_space(1))) void*)g,
        (__attribute__((address_space(3))) void*)lds,
        16, 0, 0);
}

__device__ __forceinline__ float fsig(float x) {
    return __builtin_amdgcn_rcpf(1.0f + __expf(-x));
}
__device__ __forceinline__ float ftanh(float x) {
    return 2.0f * __builtin_amdgcn_rcpf(1.0f + __expf(-2.0f * x)) - 1.0f;
}

// A LDS half = 16 KB; stored chunk = logical ^ (row&7), realized as linear
// LDS dest + inverse-permuted global source (rule 21).
__device__ __forceinline__ void stage_A(const char* Ab, int X, int t, char* slot,
                                        int wave, int r0, int cb) {
    const char* s = Ab + (size_t)(X * 64 + r0) * KB + t * 128 + cb;
    async16(slot + wave * 1024, s);
    async16(slot + (wave + 8) * 1024, s + (size_t)128 * KB);
}

__device__ __forceinline__ void read_A(bf16x8 (&d)[4][2], const char* hb,
                                       int ar, int kc0, int kc1) {
#pragma unroll
    for (int m = 0; m < 4; ++m) {
        d[m][0] = *(const bf16x8*)(hb + ar + m * 2048 + kc0);
        d[m][1] = *(const bf16x8*)(hb + ar + m * 2048 + kc1);
    }
}

// B fragment set (Y, tile t): dst[j][kk] <- Wf unit base + t*2048 + kk*1024
// + j*131072 (n16 stride = 128 ks * 1024 B).
#define LOADB(dst, bYbase, t_) {                                              \
    const char* _p = WfB + (bYbase) + (size_t)(t_) * 2048;                    \
    dst[0][0] = *(const bf16x8*)(_p);                                         \
    dst[0][1] = *(const bf16x8*)(_p + 1024);                                  \
    dst[1][0] = *(const bf16x8*)(_p + 131072);                                \
    dst[1][1] = *(const bf16x8*)(_p + 131072 + 1024); }

__device__ __forceinline__ void mfma16(f32x4 (&acc)[8][4], int mh, int Y,
                                       const bf16x8 (&a)[4][2],
                                       const bf16x8 (&b)[2][2]) {
#pragma unroll
    for (int m = 0; m < 4; ++m)
#pragma unroll
        for (int j = 0; j < 2; ++j) {
            acc[mh * 4 + m][Y * 2 + j] = __builtin_amdgcn_mfma_f32_16x16x32_bf16(
                a[m][0], b[j][0], acc[mh * 4 + m][Y * 2 + j], 0, 0, 0);
            acc[mh * 4 + m][Y * 2 + j] = __builtin_amdgcn_mfma_f32_16x16x32_bf16(
                a[m][1], b[j][1], acc[mh * 4 + m][Y * 2 + j], 0, 0, 0);
        }
}

// ---- concat(prev_state, x) -> bf16 A [MDIM][KDIM] -------------------------
__global__ __launch_bounds__(256) void k_concat_cast(
        const float* __restrict__ prev, const float* __restrict__ x,
        __hip_bfloat16* __restrict__ A) {
    const size_t total8 = (size_t)MDIM * KDIM / 8;
    const size_t stride = (size_t)gridDim.x * blockDim.x;
    for (size_t i = (size_t)blockIdx.x * blockDim.x + threadIdx.x; i < total8;
         i += stride) {
        size_t e = i * 8;
        size_t b = e >> 12;
        int k = (int)(e & (KDIM - 1));
        const float* src = (k < HDIM) ? (prev + b * HDIM + k)
                                      : (x + b * HDIM + (k - HDIM));
        float4 v0 = *(const float4*)src;
        float4 v1 = *(const float4*)(src + 4);
        union { __hip_bfloat16 h[8]; int4 q; } u;
        u.h[0] = __float2bfloat16(v0.x); u.h[1] = __float2bfloat16(v0.y);
        u.h[2] = __float2bfloat16(v0.z); u.h[3] = __float2bfloat16(v0.w);
        u.h[4] = __float2bfloat16(v1.x); u.h[5] = __float2bfloat16(v1.y);
        u.h[6] = __float2bfloat16(v1.z); u.h[7] = __float2bfloat16(v1.w);
        *(int4*)(A + e) = u.q;
    }
}

// ---- W -> fragment-linear Wf: unit u=(n16*128+ks)*64+lane, 16 B each ------
// lane = (k_chunk<<4)|r: covers row n16*16+r, k = ks*32 + k_chunk*8 (8 bf16).
// Gate interleave: n -> gate n&3, h = n>>2.
__global__ __launch_bounds__(256) void k_cast_w(
        const float* __restrict__ w0, const float* __restrict__ w1,
        const float* __restrict__ w2, const float* __restrict__ w3,
        __hip_bfloat16* __restrict__ Wf) {
    const size_t total = (size_t)512 * 128 * 64;      // 16B units
    const size_t stride = (size_t)gridDim.x * blockDim.x;
    for (size_t u = (size_t)blockIdx.x * blockDim.x + threadIdx.x; u < total;
         u += stride) {
        int lane = (int)(u & 63);
        int ks   = (int)((u >> 6) & 127);
        int n16  = (int)(u >> 13);
        int r    = lane & 15, cch = lane >> 4;
        int n = n16 * 16 + r;
        int g = n & 3;
        size_t h = (size_t)(n >> 2);
        int k = ks * 32 + cch * 8;
        const float* src = (g == 0 ? w0 : g == 1 ? w1 : g == 2 ? w2 : w3)
                           + h * KDIM + k;
        float4 v0 = *(const float4*)src;
        float4 v1 = *(const float4*)(src + 4);
        union { __hip_bfloat16 hh[8]; int4 q; } uu;
        uu.hh[0] = __float2bfloat16(v0.x); uu.hh[1] = __float2bfloat16(v0.y);
        uu.hh[2] = __float2bfloat16(v0.z); uu.hh[3] = __float2bfloat16(v0.w);
        uu.hh[4] = __float2bfloat16(v1.x); uu.hh[5] = __float2bfloat16(v1.y);
        uu.hh[6] = __float2bfloat16(v1.z); uu.hh[7] = __float2bfloat16(v1.w);
        *(int4*)((char*)Wf + u * 16) = uu.q;
    }
}

// ---- GEMM + fused LSTM cell epilogue ---------------------------------------
__global__ __launch_bounds__(512, 2) void k_gemm(
        const __hip_bfloat16* __restrict__ A, const __hip_bfloat16* __restrict__ Wf,
        const float* __restrict__ c, float* __restrict__ out) {
    __shared__ __align__(16) char lds[65536];         // 4 A-halves only

    // 2-D XCD swizzle: XCD (bid&7) owns an 8(mt) x 8(nt) sub-grid (bijective)
    const int bid = blockIdx.x;
    const int xcd = bid & 7, j = bid >> 3;
    const int mt = (xcd >> 2) * 8 + (j >> 3);
    const int nt = (xcd & 3) * 8 + (j & 7);
    const int brow = mt * 256, bcol = nt * 256;

    const int tid = threadIdx.x;
    const int wave = tid >> 6, lane = tid & 63;
    const int wr = wave >> 2, wc = wave & 3;

    const char* Ab  = (const char*)A + (size_t)brow * KB;
    const char* WfB = (const char*)Wf;

    char* const Ah00 = lds;
    char* const Ah01 = lds + 16384;
    char* const Ah10 = lds + 32768;
    char* const Ah11 = lds + 49152;

    const int r0  = wave * 8 + (lane >> 3);
    const int cb  = (((lane & 7) ^ (lane >> 3)) << 4);
    const int kg  = lane >> 4;
    const int ar  = (wr * 64 + (lane & 15)) * 128;
    const int kc0 = ((kg ^ (lane & 7)) << 4);
    const int kc1 = (((4 + kg) ^ (lane & 7)) << 4);

    // B fragment bases: n16 = bcol/16 + wc*4 + Y*2 (+j); byte = n16*131072
    const size_t n16b = (size_t)(bcol >> 4) + wc * 4;
    const size_t bY0 = n16b * 131072 + (size_t)lane * 16;
    const size_t bY1 = (n16b + 2) * 131072 + (size_t)lane * 16;

    f32x4 acc[8][4] = {};
    bf16x8 a0[4][2], a1[4][2], bv0[2][2], bv1[2][2];

    // ---- prologue: stage A tiles 0,1 (8 gll); load B(t0,Y0) (4) ----
    stage_A(Ab, 0, 0, Ah00, wave, r0, cb);
    stage_A(Ab, 1, 0, Ah01, wave, r0, cb);
    stage_A(Ab, 0, 1, Ah10, wave, r0, cb);
    stage_A(Ab, 1, 1, Ah11, wave, r0, cb);
    LOADB(bv0, bY0, 0);
    VMW8;                     // certify Ah00 (10 after), Ah01 (8 after)
    SB0; BAR;
    read_A(a0, Ah00, ar, kc0, kc1);
    LGKM0;                    // drain before r2 restages Ah00
    SB0; BAR;

    // ---- main loop: 32 iters x 2 K-tiles (ta=2i, tb=2i+1) ----
    for (int i = 0; i < 32; ++i) {
        const int ta = 2 * i;
        const int tb = 2 * i + 1;
        const int t2 = (2 * i + 2) & 63;
        const int t3 = (2 * i + 3) & 63;

        // r1: load bv1=B(ta,Y1); read a1<-Ah01; MFMA (0,0)[a0,bv0]
        LOADB(bv1, bY1, ta);
        SB0;
        read_A(a1, Ah01, ar, kc0, kc1);
        SB0;
        PRIO1; mfma16(acc, 0, 0, a0, bv0); PRIO0;
        LGKM0; SB0;
        // r2: stage Ah00<-t2; MFMA (1,0)[a1,bv0]; VMW12; BAR
        stage_A(Ab, 0, t2, Ah00, wave, r0, cb);
        SB0;
        PRIO1; mfma16(acc, 1, 0, a1, bv0); PRIO0;
        VMW12; SB0; BAR;
        // r3: load bv0=B(tb,Y0); stage Ah01<-t2; MFMA (1,1)[a1,bv1]
        LOADB(bv0, bY0, tb);
        SB0;
        stage_A(Ab, 1, t2, Ah01, wave, r0, cb);
        SB0;
        PRIO1; mfma16(acc, 1, 1, a1, bv1); PRIO0;
        SB0;
        // r4: read a1<-Ah10; MFMA (0,1)[a0,bv1]; LGKM0; VMW12; BAR
        read_A(a1, Ah10, ar, kc0, kc1);
        SB0;
        PRIO1; mfma16(acc, 0, 1, a0, bv1); PRIO0;
        LGKM0; VMW12; SB0; BAR;
        // r5: load bv1=B(tb,Y1); read a0<-Ah11; MFMA (0,0)[a1,bv0]
        LOADB(bv1, bY1, tb);
        SB0;
        read_A(a0, Ah11, ar, kc0, kc1);
        SB0;
        PRIO1; mfma16(acc, 0, 0, a1, bv0); PRIO0;
        LGKM0; SB0;
        // r6: stage Ah10<-t3; MFMA (1,0)[a0,bv0]; VMW12; BAR
        stage_A(Ab, 0, t3, Ah10, wave, r0, cb);
        SB0;
        PRIO1; mfma16(acc, 1, 0, a0, bv0); PRIO0;
        VMW12; SB0; BAR;
        // r7: load bv0=B(t2,Y0) [next iter]; stage Ah11<-t3; MFMA (1,1)[a0,bv1]
        LOADB(bv0, bY0, t2);
        SB0;
        stage_A(Ab, 1, t3, Ah11, wave, r0, cb);
        SB0;
        PRIO1; mfma16(acc, 1, 1, a0, bv1); PRIO0;
        SB0;
        // r8: read a0<-Ah00; MFMA (0,1)[a1,bv1]; LGKM0; VMW12; BAR
        read_A(a0, Ah00, ar, kc0, kc1);
        SB0;
        PRIO1; mfma16(acc, 0, 1, a1, bv1); PRIO0;
        LGKM0; VMW12; SB0; BAR;
    }

    // ---- fused cell epilogue: two 128-row passes through LDS ----
    VMW0; LGKM0;
    BAR;
    __hip_bfloat16* cl = (__hip_bfloat16*)lds;      // [128][256] bf16 = 64 KB
    const int h0 = bcol >> 2;
    #pragma unroll
    for (int p = 0; p < 2; ++p) {
        if (p) BAR;
        if (wr == p) {
            const int rb = ((lane >> 4) << 2);
            const int cbase = wc * 64 + (lane & 15);
            #pragma unroll
            for (int mi = 0; mi < 8; ++mi)
                #pragma unroll
                for (int ni = 0; ni < 4; ++ni)
                    #pragma unroll
                    for (int q = 0; q < 4; ++q)
                        cl[(rb + mi * 16 + q) * 256 + (cbase + ni * 16)] =
                            __float2bfloat16(acc[mi][ni][q]);
        }
        BAR;
        #pragma unroll
        for (int rnd = 0; rnd < 4; ++rnd) {
            const int row = rnd * 32 + (tid >> 4);
            const int ccol = (tid & 15) * 16;
            union { int4 q[2]; __hip_bfloat16 h[16]; } v;
            v.q[0] = *(const int4*)&cl[row * 256 + ccol];
            v.q[1] = *(const int4*)&cl[row * 256 + ccol + 8];
            const size_t R = (size_t)(brow + p * 128 + row);
            const int hh = h0 + (tid & 15) * 4;
            float4 cc = *(const float4*)(c + R * HDIM + hh);
            float cs[4] = {cc.x, cc.y, cc.z, cc.w};
            float ht[4];
            #pragma unroll
            for (int u = 0; u < 4; ++u) {
                float ft  = fsig(__bfloat162float(v.h[4 * u + 0]));
                float it  = fsig(__bfloat162float(v.h[4 * u + 1]));
                float ctt = fsig(__bfloat162float(v.h[4 * u + 2]));
                float ot  = fsig(__bfloat162float(v.h[4 * u + 3]));
                float ct  = ft * cs[u] + it * ctt;
                ht[u] = ot * ftanh(ct);
            }
            float4 o = {ht[0], ht[1], ht[2], ht[3]};
            *(float4*)(out + R * HDIM + hh) = o;
        }
    }
}

extern "C" void kernel_launch(void* const* d_in, const int* in_sizes, int n_in,
                              void* d_out, int out_size, void* d_ws, size_t ws_size,
                              hipStream_t stream) {
    const float* x    = (const float*)d_in[0];
    const float* prev = (const float*)d_in[1];
    const float* cst  = (const float*)d_in[2];
    const float* wfg  = (const float*)d_in[3];
    const float* wig  = (const float*)d_in[4];
    const float* wog  = (const float*)d_in[5];
    const float* wol  = (const float*)d_in[6];
    float* out = (float*)d_out;

    char* ws = (char*)d_ws;
    __hip_bfloat16* Abf = (__hip_bfloat16*)(ws);                 // 32 MB
    __hip_bfloat16* Wbf = (__hip_bfloat16*)(ws + 33554432);      // 64 MB

    k_concat_cast<<<2048, 256, 0, stream>>>(prev, x, Abf);
    k_cast_w<<<2048, 256, 0, stream>>>(wfg, wig, wog, wol, Wbf);
    k_gemm<<<512, 512, 0, stream>>>(Abf, Wbf, cst, out);
}

// Round 13
// 268.597 us; speedup vs baseline: 1.0403x; 1.0403x over previous
//
#include <hip/hip_runtime.h>
#include <hip/hip_bf16.h>
#include <cstdint>
#include <cstddef>

// ---------------------------------------------------------------------------
// LSTM cell: ht = sigmoid(o) * tanh(sigmoid(f)*c + sigmoid(i)*sigmoid(c~))
// gates = [prev_state, x] @ W'^T with W' row-interleaved: W'[4h+g] = W_g[h].
// Cell update fused into GEMM epilogue (gates never touch HBM).
// GEMM core (= round-11 verified): 256x256, BK=64, 8 regions per 2 K-tiles,
// BAR every 2nd region, stage-certify vmcnt(4) at ends of r4/r8 only.
// THIS ROUND: revert round-12's B-direct regression; single-pass fused
// epilogue (full 256x256 bf16 C-tile in 128 KB LDS, all 8 waves write).
// ---------------------------------------------------------------------------

typedef __bf16 nbf16;
typedef nbf16 bf16x8 __attribute__((ext_vector_type(8)));
typedef float f32x4 __attribute__((ext_vector_type(4)));

static constexpr int MDIM = 4096;
static constexpr int NDIM = 8192;
static constexpr int KDIM = 4096;
static constexpr int HDIM = 2048;
static constexpr int KB   = KDIM * 2;     // K row stride in bytes

#define VMW4  asm volatile("s_waitcnt vmcnt(4)" ::: "memory")
#define VMW0  asm volatile("s_waitcnt vmcnt(0)" ::: "memory")
#define LGKM0 asm volatile("s_waitcnt lgkmcnt(0)" ::: "memory")
#define BAR   __builtin_amdgcn_s_barrier()
#define SB0   __builtin_amdgcn_sched_barrier(0)
#define PRIO1 __builtin_amdgcn_s_setprio(1)
#define PRIO0 __builtin_amdgcn_s_setprio(0)

__device__ __forceinline__ void async16(void* lds, const void* g) {
    __builtin_amdgcn_global_load_lds(
        (const __attribute__((address_space(1))) void*)g,
        (__attribute__((address_space(3))) void*)lds,
        16, 0, 0);
}

__device__ __forceinline__ float fsig(float x) {
    return __builtin_amdgcn_rcpf(1.0f + __expf(-x));
}
__device__ __forceinline__ float ftanh(float x) {
    return 2.0f * __builtin_amdgcn_rcpf(1.0f + __expf(-2.0f * x)) - 1.0f;
}

// LDS half = 128 rows x 64 k bf16 = 16 KB; stored chunk = logical ^ (row&7),
// realized as linear LDS dest + inverse-permuted global source (rule 21).
__device__ __forceinline__ void stage_A(const char* Ab, int X, int t, char* slot,
                                        int wave, int r0, int cb) {
    const char* s = Ab + (size_t)(X * 64 + r0) * KB + t * 128 + cb;
    async16(slot + wave * 1024, s);
    async16(slot + (wave + 8) * 1024, s + (size_t)128 * KB);
}
__device__ __forceinline__ void stage_B(const char* Wb, int Y, int t, char* slot,
                                        int wave, int rB0, int cb) {
    const char* s = Wb + (size_t)(rB0 + Y * 32) * KB + t * 128 + cb;
    async16(slot + wave * 1024, s);
    async16(slot + (wave + 8) * 1024, s + (size_t)128 * KB);
}

__device__ __forceinline__ void read_A(bf16x8 (&d)[4][2], const char* hb,
                                       int ar, int kc0, int kc1) {
#pragma unroll
    for (int m = 0; m < 4; ++m) {
        d[m][0] = *(const bf16x8*)(hb + ar + m * 2048 + kc0);
        d[m][1] = *(const bf16x8*)(hb + ar + m * 2048 + kc1);
    }
}
__device__ __forceinline__ void read_B(bf16x8 (&d)[2][2], const char* hb,
                                       int br, int kc0, int kc1) {
#pragma unroll
    for (int j = 0; j < 2; ++j) {
        d[j][0] = *(const bf16x8*)(hb + br + j * 2048 + kc0);
        d[j][1] = *(const bf16x8*)(hb + br + j * 2048 + kc1);
    }
}
__device__ __forceinline__ void mfma16(f32x4 (&acc)[8][4], int mh, int Y,
                                       const bf16x8 (&a)[4][2],
                                       const bf16x8 (&b)[2][2]) {
#pragma unroll
    for (int m = 0; m < 4; ++m)
#pragma unroll
        for (int j = 0; j < 2; ++j) {
            acc[mh * 4 + m][Y * 2 + j] = __builtin_amdgcn_mfma_f32_16x16x32_bf16(
                a[m][0], b[j][0], acc[mh * 4 + m][Y * 2 + j], 0, 0, 0);
            acc[mh * 4 + m][Y * 2 + j] = __builtin_amdgcn_mfma_f32_16x16x32_bf16(
                a[m][1], b[j][1], acc[mh * 4 + m][Y * 2 + j], 0, 0, 0);
        }
}

// ---- concat(prev_state, x) -> bf16 A [MDIM][KDIM] -------------------------
__global__ __launch_bounds__(256) void k_concat_cast(
        const float* __restrict__ prev, const float* __restrict__ x,
        __hip_bfloat16* __restrict__ A) {
    const size_t total8 = (size_t)MDIM * KDIM / 8;
    const size_t stride = (size_t)gridDim.x * blockDim.x;
    for (size_t i = (size_t)blockIdx.x * blockDim.x + threadIdx.x; i < total8;
         i += stride) {
        size_t e = i * 8;
        size_t b = e >> 12;
        int k = (int)(e & (KDIM - 1));
        const float* src = (k < HDIM) ? (prev + b * HDIM + k)
                                      : (x + b * HDIM + (k - HDIM));
        float4 v0 = *(const float4*)src;
        float4 v1 = *(const float4*)(src + 4);
        union { __hip_bfloat16 h[8]; int4 q; } u;
        u.h[0] = __float2bfloat16(v0.x); u.h[1] = __float2bfloat16(v0.y);
        u.h[2] = __float2bfloat16(v0.z); u.h[3] = __float2bfloat16(v0.w);
        u.h[4] = __float2bfloat16(v1.x); u.h[5] = __float2bfloat16(v1.y);
        u.h[6] = __float2bfloat16(v1.z); u.h[7] = __float2bfloat16(v1.w);
        *(int4*)(A + e) = u.q;
    }
}

// ---- gate-interleaved W': row n = W_{n&3}[n>>2], bf16 [NDIM][KDIM] ---------
__global__ __launch_bounds__(256) void k_cast_w(
        const float* __restrict__ w0, const float* __restrict__ w1,
        const float* __restrict__ w2, const float* __restrict__ w3,
        __hip_bfloat16* __restrict__ W) {
    const size_t total8 = (size_t)NDIM * KDIM / 8;
    const size_t stride = (size_t)gridDim.x * blockDim.x;
    for (size_t i = (size_t)blockIdx.x * blockDim.x + threadIdx.x; i < total8;
         i += stride) {
        size_t e = i * 8;
        int n = (int)(e >> 12);
        int k = (int)(e & (KDIM - 1));
        int g = n & 3;
        size_t h = (size_t)(n >> 2);
        const float* src = (g == 0 ? w0 : g == 1 ? w1 : g == 2 ? w2 : w3)
                           + h * KDIM + k;
        float4 v0 = *(const float4*)src;
        float4 v1 = *(const float4*)(src + 4);
        union { __hip_bfloat16 h[8]; int4 q; } u;
        u.h[0] = __float2bfloat16(v0.x); u.h[1] = __float2bfloat16(v0.y);
        u.h[2] = __float2bfloat16(v0.z); u.h[3] = __float2bfloat16(v0.w);
        u.h[4] = __float2bfloat16(v1.x); u.h[5] = __float2bfloat16(v1.y);
        u.h[6] = __float2bfloat16(v1.z); u.h[7] = __float2bfloat16(v1.w);
        *(int4*)(W + e) = u.q;
    }
}

// ---- GEMM + fused LSTM cell epilogue ---------------------------------------
__global__ __launch_bounds__(512, 2) void k_gemm(
        const __hip_bfloat16* __restrict__ A, const __hip_bfloat16* __restrict__ W,
        const float* __restrict__ c, float* __restrict__ out) {
    __shared__ __align__(16) char lds[131072];

    // 2-D XCD swizzle: XCD (bid&7) owns an 8(mt) x 8(nt) sub-grid (bijective)
    const int bid = blockIdx.x;
    const int xcd = bid & 7, j = bid >> 3;
    const int mt = (xcd >> 2) * 8 + (j >> 3);
    const int nt = (xcd & 3) * 8 + (j & 7);
    const int brow = mt * 256, bcol = nt * 256;

    const int tid = threadIdx.x;
    const int wave = tid >> 6, lane = tid & 63;
    const int wr = wave >> 2, wc = wave & 3;

    const char* Ab = (const char*)A + (size_t)brow * KB;
    const char* Wb = (const char*)W + (size_t)bcol * KB;

    char* const Ah00 = lds;
    char* const Ah01 = lds + 16384;
    char* const Ah10 = lds + 32768;
    char* const Ah11 = lds + 49152;
    char* const Bh00 = lds + 65536;
    char* const Bh01 = lds + 81920;
    char* const Bh10 = lds + 98304;
    char* const Bh11 = lds + 114688;

    const int r0  = wave * 8 + (lane >> 3);
    const int rB0 = ((r0 >> 5) << 6) + (r0 & 31);
    const int cb  = (((lane & 7) ^ (lane >> 3)) << 4);
    const int kg  = lane >> 4;
    const int ar  = (wr * 64 + (lane & 15)) * 128;
    const int br  = (wc * 32 + (lane & 15)) * 128;
    const int kc0 = ((kg ^ (lane & 7)) << 4);
    const int kc1 = (((4 + kg) ^ (lane & 7)) << 4);

    f32x4 acc[8][4] = {};
    bf16x8 a0[4][2], a1[4][2], b0[2][2], b1[2][2];

    // ---- prologue: stage tiles 0 (s0) and 1 (s1) ----
    stage_B(Wb, 0, 0, Bh00, wave, rB0, cb);
    stage_A(Ab, 0, 0, Ah00, wave, r0, cb);
    stage_A(Ab, 1, 0, Ah01, wave, r0, cb);
    stage_B(Wb, 1, 0, Bh01, wave, rB0, cb);
    stage_B(Wb, 0, 1, Bh10, wave, rB0, cb);
    stage_A(Ab, 0, 1, Ah10, wave, r0, cb);
    stage_A(Ab, 1, 1, Ah11, wave, r0, cb);
    stage_B(Wb, 1, 1, Bh11, wave, rB0, cb);
    VMW4;                     // certify first 12 gll (through Ah10)
    SB0; BAR;
    read_A(a0, Ah00, ar, kc0, kc1);
    read_B(b0, Bh00, br, kc0, kc1);
    LGKM0;                    // drain pre-loop reads before r1 restages Bh00
    SB0; BAR;                 // even boundary anchoring the loop period

    // ---- main loop: 32 iters x 2 K-tiles; 8 regions; BAR every 2nd region;
    //      stage-certify vmcnt(4) only at ends of r4 and r8 ----
    for (int i = 0; i < 32; ++i) {
        const int t2 = (2 * i + 2) & 63;
        const int t3 = (2 * i + 3) & 63;

        // r1 (odd): reads A-hi(s0)->a1; stage B-lo(s0,t2); MFMA [a0,b0]
        read_A(a1, Ah01, ar, kc0, kc1);
        stage_B(Wb, 0, t2, Bh00, wave, rB0, cb);
        SB0;
        PRIO1; mfma16(acc, 0, 0, a0, b0); PRIO0;
        LGKM0; SB0;
        // r2 (even, BAR): reads B-hi(s0)->b1; stage A-lo(s0,t2); MFMA [a1,b0]
        read_B(b1, Bh01, br, kc0, kc1);
        stage_A(Ab, 0, t2, Ah00, wave, r0, cb);
        SB0;
        PRIO1; mfma16(acc, 1, 0, a1, b0); PRIO0;
        LGKM0; SB0; BAR;
        // r3 (odd): reads B-lo(s1)->b0; stage A-hi(s0,t2); MFMA [a1,b1]
        read_B(b0, Bh10, br, kc0, kc1);
        stage_A(Ab, 1, t2, Ah01, wave, r0, cb);
        SB0;
        PRIO1; mfma16(acc, 1, 1, a1, b1); PRIO0;
        LGKM0; SB0;
        // r4 (even, VMW4+BAR): reads A-lo(s1)->a1; stage B-hi(s0,t2); MFMA [a0,b1]
        read_A(a1, Ah10, ar, kc0, kc1);
        stage_B(Wb, 1, t2, Bh01, wave, rB0, cb);
        SB0;
        PRIO1; mfma16(acc, 0, 1, a0, b1); PRIO0;
        LGKM0; VMW4; SB0; BAR;
        // r5 (odd): reads A-hi(s1)->a0; stage B-lo(s1,t3); MFMA [a1,b0]
        read_A(a0, Ah11, ar, kc0, kc1);
        stage_B(Wb, 0, t3, Bh10, wave, rB0, cb);
        SB0;
        PRIO1; mfma16(acc, 0, 0, a1, b0); PRIO0;
        LGKM0; SB0;
        // r6 (even, BAR): reads B-hi(s1)->b1; stage A-lo(s1,t3); MFMA [a0,b0]
        read_B(b1, Bh11, br, kc0, kc1);
        stage_A(Ab, 0, t3, Ah10, wave, r0, cb);
        SB0;
        PRIO1; mfma16(acc, 1, 0, a0, b0); PRIO0;
        LGKM0; SB0; BAR;
        // r7 (odd): reads B-lo(s0,t2)->b0; stage A-hi(s1,t3); MFMA [a0,b1]
        read_B(b0, Bh00, br, kc0, kc1);
        stage_A(Ab, 1, t3, Ah11, wave, r0, cb);
        SB0;
        PRIO1; mfma16(acc, 1, 1, a0, b1); PRIO0;
        LGKM0; SB0;
        // r8 (even, VMW4+BAR): reads A-lo(s0,t2)->a0; stage B-hi(s1,t3); MFMA [a1,b1]
        read_A(a0, Ah00, ar, kc0, kc1);
        stage_B(Wb, 1, t3, Bh11, wave, rB0, cb);
        SB0;
        PRIO1; mfma16(acc, 0, 1, a1, b1); PRIO0;
        LGKM0; VMW4; SB0; BAR;
    }

    // ---- fused cell epilogue: SINGLE pass through 128 KB LDS C-tile ----
    VMW0; LGKM0;
    BAR;
    __hip_bfloat16* cl = (__hip_bfloat16*)lds;      // [256][256] bf16 = 128 KB
    const int h0 = bcol >> 2;
    {
        const int rb = wr * 128 + ((lane >> 4) << 2);
        const int cbase = wc * 64 + (lane & 15);
        #pragma unroll
        for (int mi = 0; mi < 8; ++mi)
            #pragma unroll
            for (int ni = 0; ni < 4; ++ni)
                #pragma unroll
                for (int q = 0; q < 4; ++q)
                    cl[(rb + mi * 16 + q) * 256 + (cbase + ni * 16)] =
                        __float2bfloat16(acc[mi][ni][q]);
    }
    BAR;
    #pragma unroll
    for (int rnd = 0; rnd < 8; ++rnd) {
        const int row = rnd * 32 + (tid >> 4);
        const int ccol = (tid & 15) * 16;
        union { int4 q[2]; __hip_bfloat16 h[16]; } v;
        v.q[0] = *(const int4*)&cl[row * 256 + ccol];
        v.q[1] = *(const int4*)&cl[row * 256 + ccol + 8];
        const size_t R = (size_t)(brow + row);
        const int hh = h0 + (tid & 15) * 4;
        float4 cc = *(const float4*)(c + R * HDIM + hh);
        float cs[4] = {cc.x, cc.y, cc.z, cc.w};
        float ht[4];
        #pragma unroll
        for (int u = 0; u < 4; ++u) {
            float ft  = fsig(__bfloat162float(v.h[4 * u + 0]));
            float it  = fsig(__bfloat162float(v.h[4 * u + 1]));
            float ctt = fsig(__bfloat162float(v.h[4 * u + 2]));
            float ot  = fsig(__bfloat162float(v.h[4 * u + 3]));
            float ct  = ft * cs[u] + it * ctt;
            ht[u] = ot * ftanh(ct);
        }
        float4 o = {ht[0], ht[1], ht[2], ht[3]};
        *(float4*)(out + R * HDIM + hh) = o;
    }
}

extern "C" void kernel_launch(void* const* d_in, const int* in_sizes, int n_in,
                              void* d_out, int out_size, void* d_ws, size_t ws_size,
                              hipStream_t stream) {
    const float* x    = (const float*)d_in[0];
    const float* prev = (const float*)d_in[1];
    const float* cst  = (const float*)d_in[2];
    const float* wfg  = (const float*)d_in[3];
    const float* wig  = (const float*)d_in[4];
    const float* wog  = (const float*)d_in[5];
    const float* wol  = (const float*)d_in[6];
    float* out = (float*)d_out;

    char* ws = (char*)d_ws;
    __hip_bfloat16* Abf = (__hip_bfloat16*)(ws);                 // 32 MB
    __hip_bfloat16* Wbf = (__hip_bfloat16*)(ws + 33554432);      // 64 MB

    k_concat_cast<<<2048, 256, 0, stream>>>(prev, x, Abf);
    k_cast_w<<<2048, 256, 0, stream>>>(wfg, wig, wog, wol, Wbf);
    k_gemm<<<512, 512, 0, stream>>>(Abf, Wbf, cst, out);
}